// Round 3
// baseline (359.157 us; speedup 1.0000x reference)
//
#include <hip/hip_runtime.h>
#include <stdint.h>

typedef __attribute__((ext_vector_type(4))) float f32x4;
typedef __attribute__((ext_vector_type(8))) short s16x8;
typedef __attribute__((ext_vector_type(4))) short s16x4;

struct Params {
  const float* cls_feat[3];
  const float* reg_feat[3];
  const float* obj_w[3];
  const float* obj_b[3];
  const float* cls_w[3];
  const float* cls_b[3];
  const float* reg_w[3];
  const float* reg_b[3];
  float* out;
};

__device__ __forceinline__ unsigned short f2bf(float f) {
  unsigned int u = __builtin_bit_cast(unsigned int, f);
  u = (u + 0x7FFFu + ((u >> 16) & 1u)) >> 16;  // RNE
  return (unsigned short)u;
}

__device__ __forceinline__ s16x8 cvt8(f32x4 a, f32x4 b, bool valid) {
  s16x8 r;
  #pragma unroll
  for (int j = 0; j < 4; ++j) {
    r[j]     = valid ? (short)f2bf(a[j]) : (short)0;
    r[4 + j] = valid ? (short)f2bf(b[j]) : (short)0;
  }
  return r;
}

// Transpose-convert 4 m x 4 ch into LDS [m][k] bf16.
// Chunk16 layout: row = 256 shorts = 32 chunks of 16B. Iter i covers chunks
// 8i..8i+7; within the 8-chunk group, chunk low3 = (tq>>1) ^ key(m),
// key(m) = ((m>>2)^m)&7 -- same involution the GEMM read applies.
__device__ __forceinline__ void stage4(short* lds, int mq, int tq, int i,
                                       f32x4 L0, f32x4 L1, f32x4 L2, f32x4 L3) {
  #pragma unroll
  for (int j = 0; j < 4; ++j) {
    const int m   = mq * 4 + j;
    const int key = ((m >> 2) ^ m) & 7;
    const int swc = (tq >> 1) ^ key;
    s16x4 h;
    h[0] = (short)f2bf(L0[j]); h[1] = (short)f2bf(L1[j]);
    h[2] = (short)f2bf(L2[j]); h[3] = (short)f2bf(L3[j]);
    *(s16x4*)&lds[m * 256 + i * 64 + swc * 8 + (tq & 1) * 4] = h;
  }
}

// m-tile = 80 (divides 6400/1600/400 -> no partial tiles). LDS 40960 B -> 4 blocks/CU.
__global__ __launch_bounds__(320, 5) void head_kernel(Params p) {
  const int tid  = threadIdx.x;
  const int lane = tid & 63;
  const int wave = tid >> 6;      // 0..4, one 16-row o-tile each
  const int quad = lane >> 4;     // 0..3
  const int col  = lane & 15;
  const bool is_cls = (blockIdx.y == 0);

  // block -> (batch, level, m-tile). 105 tiles/batch: 80 + 20 + 5
  int bx = blockIdx.x;
  int b  = bx / 105;
  int t  = bx - b * 105;
  int level, tloc;
  if (t < 80)       { level = 0; tloc = t; }
  else if (t < 100) { level = 1; tloc = t - 80; }
  else              { level = 2; tloc = t - 100; }

  const int   LW_[3]   = {80, 40, 20};
  const float LS_[3]   = {8.f, 16.f, 32.f};
  const int   LOFF_[3] = {0, 6400, 8000};
  const int   LM_[3]   = {6400, 1600, 400};

  const int   Mlvl = LM_[level];
  const int   Moff = LOFF_[level];
  const float strd = LS_[level];
  const int   m0   = tloc * 80;

  __shared__ __align__(16) short lds_feat[80 * 256];  // 40960 B

  const f32x4 vzero = {0.f, 0.f, 0.f, 0.f};

  // staging decomposition: thread -> (tq = channel slot 0..15, mq = m-quad 0..19)
  const int tq = tid / 20;
  const int mq = tid - tq * 20;

  const float* featp = (is_cls ? p.cls_feat[level] : p.reg_feat[level])
                       + (size_t)b * 256 * (size_t)Mlvl + m0 + mq * 4;

  // weight row for this lane's A-fragment
  const int orow = wave * 16 + col;
  const float* wptr;
  if (is_cls)          wptr = p.cls_w[level] + orow * 256;
  else if (orow < 64)  wptr = p.reg_w[level] + orow * 256;
  else if (orow == 64) wptr = p.obj_w[level];
  else                 wptr = nullptr;
  const bool  wvalid = (wptr != nullptr);
  const float* wq    = (wvalid ? wptr : p.obj_w[level]) + quad * 8;

  #define WLD(s, h) (*(const f32x4*)(wq + (s) * 32 + (h) * 4))
  #define FLD(i, c) (*(const f32x4*)(featp + (size_t)((i) * 64 + tq * 4 + (c)) * (size_t)Mlvl))

  // ---- issue/consume ladder (FIFO-ordered: every wait retires a proper prefix,
  //      keeping 12-16 dwordx4 loads in flight per thread) ----
  s16x8 afrag[8];
  f32x4 wa, wb, wc, wd;
  f32x4 A0, A1, A2, A3, B0, B1, B2, B3;

  wa = WLD(0, 0); wb = WLD(0, 1); wc = WLD(1, 0); wd = WLD(1, 1);      // W chunk0
  A0 = FLD(0, 0); A1 = FLD(0, 1); A2 = FLD(0, 2); A3 = FLD(0, 3);     // F iter0
  B0 = FLD(1, 0); B1 = FLD(1, 1); B2 = FLD(1, 2); B3 = FLD(1, 3);     // F iter1

  f32x4 bias = vzero;
  {
    const int o0 = wave * 16 + quad * 4;
    if (is_cls)        bias = *(const f32x4*)(p.cls_b[level] + o0);
    else if (o0 < 64)  bias = *(const f32x4*)(p.reg_b[level] + o0);
    else if (o0 == 64) bias[0] = p.obj_b[level][0];
  }

  afrag[0] = cvt8(wa, wb, wvalid); afrag[1] = cvt8(wc, wd, wvalid);    // consume W0
  wa = WLD(2, 0); wb = WLD(2, 1); wc = WLD(3, 0); wd = WLD(3, 1);      // W chunk1
  stage4(lds_feat, mq, tq, 0, A0, A1, A2, A3);                         // consume F0
  A0 = FLD(2, 0); A1 = FLD(2, 1); A2 = FLD(2, 2); A3 = FLD(2, 3);      // F iter2
  afrag[2] = cvt8(wa, wb, wvalid); afrag[3] = cvt8(wc, wd, wvalid);    // consume W1
  wa = WLD(4, 0); wb = WLD(4, 1); wc = WLD(5, 0); wd = WLD(5, 1);      // W chunk2
  stage4(lds_feat, mq, tq, 1, B0, B1, B2, B3);                         // consume F1
  B0 = FLD(3, 0); B1 = FLD(3, 1); B2 = FLD(3, 2); B3 = FLD(3, 3);      // F iter3
  afrag[4] = cvt8(wa, wb, wvalid); afrag[5] = cvt8(wc, wd, wvalid);    // consume W2
  wa = WLD(6, 0); wb = WLD(6, 1); wc = WLD(7, 0); wd = WLD(7, 1);      // W chunk3
  stage4(lds_feat, mq, tq, 2, A0, A1, A2, A3);                         // consume F2
  afrag[6] = cvt8(wa, wb, wvalid); afrag[7] = cvt8(wc, wd, wvalid);    // consume W3
  stage4(lds_feat, mq, tq, 3, B0, B1, B2, B3);                         // consume F3

  __syncthreads();

  // ---- GEMM: D[o][m] = W[o][k] * feat[k][m], K=256, 5 m-frags/wave ----
  f32x4 acc[5];
  #pragma unroll
  for (int mf = 0; mf < 5; ++mf) acc[mf] = vzero;
  #pragma unroll
  for (int mf = 0; mf < 5; ++mf) {
    const int row  = mf * 16 + col;
    const int rkey = ((row >> 2) ^ row) & 7;
    const short* base = &lds_feat[row * 256];
    #pragma unroll
    for (int s = 0; s < 8; ++s) {
      const int c16 = 4 * s + quad;
      const int sw  = (c16 & ~7) | ((c16 & 7) ^ rkey);
      s16x8 bfrag = *(const s16x8*)(base + sw * 8);
      acc[mf] = __builtin_amdgcn_mfma_f32_16x16x32_bf16(afrag[s], bfrag, acc[mf], 0, 0, 0);
    }
  }

  // ---- epilogue ----
  const size_t outbase = (size_t)b * 8400 + Moff + m0;
  float* out = p.out;

  if (is_cls) {
    #pragma unroll
    for (int mf = 0; mf < 5; ++mf) {
      const int m = mf * 16 + col;
      f32x4 v = acc[mf] + bias;
      float* dst = out + (outbase + m) * 149 + 1 + wave * 16 + quad * 4;
      __builtin_memcpy(dst, &v, 16);
    }
    return;
  }

  // reg block: reuse feature LDS for DFL expectations after all reads complete
  float* g_lds = (float*)lds_feat;  // [4][80]
  __syncthreads();

  if (wave < 4) {
    // reg logits (ch 81..144) + DFL expectation for side f = wave
    const float projscale = 16.f / 15.f;
    #pragma unroll
    for (int mf = 0; mf < 5; ++mf) {
      const int m = mf * 16 + col;
      f32x4 v = acc[mf] + bias;
      float* dst = out + (outbase + m) * 149 + 81 + wave * 16 + quad * 4;
      __builtin_memcpy(dst, &v, 16);
      // softmax over 16 bins: 4 regs x 4 quads (same m column)
      float mx = fmaxf(fmaxf(v[0], v[1]), fmaxf(v[2], v[3]));
      mx = fmaxf(mx, __shfl_xor(mx, 16, 64));
      mx = fmaxf(mx, __shfl_xor(mx, 32, 64));
      const float e0 = __expf(v[0] - mx), e1 = __expf(v[1] - mx);
      const float e2 = __expf(v[2] - mx), e3 = __expf(v[3] - mx);
      float sden = e0 + e1 + e2 + e3;
      const float q4 = (float)(quad * 4);
      float n = q4 * e0 + (q4 + 1.f) * e1 + (q4 + 2.f) * e2 + (q4 + 3.f) * e3;
      sden += __shfl_xor(sden, 16, 64); sden += __shfl_xor(sden, 32, 64);
      n    += __shfl_xor(n, 16, 64);    n    += __shfl_xor(n, 32, 64);
      if (quad == 0) g_lds[wave * 80 + m] = projscale * n / sden;
    }
  } else {
    // wave 4: obj row (o=64 -> quad 0, reg 0)
    #pragma unroll
    for (int mf = 0; mf < 5; ++mf) {
      const int m = mf * 16 + col;
      if (quad == 0) out[(outbase + m) * 149] = acc[mf][0] + bias[0];
    }
  }

  __syncthreads();

  // box decode (wave 4): anchors +/- expectation * stride, m = 0..79
  if (wave == 4) {
    #pragma unroll
    for (int it = 0; it < 2; ++it) {
      const int m = it * 64 + lane;
      if (m < 80) {
        const float g0 = g_lds[m], g1 = g_lds[80 + m];
        const float g2 = g_lds[160 + m], g3 = g_lds[240 + m];
        const int mg = m0 + m;
        int hh;
        if (level == 0)      hh = mg / 80;
        else if (level == 1) hh = mg / 40;
        else                 hh = mg / 20;
        const int ww = mg - hh * LW_[level];
        const float ax = (ww + 0.5f) * strd;
        const float ay = (hh + 0.5f) * strd;
        f32x4 bv;
        bv[0] = ax - g0 * strd; bv[1] = ay - g1 * strd;
        bv[2] = ax + g2 * strd; bv[3] = ay + g3 * strd;
        float* dst = out + (outbase + m) * 149 + 145;
        __builtin_memcpy(dst, &bv, 16);
      }
    }
  }
}

extern "C" void kernel_launch(void* const* d_in, const int* in_sizes, int n_in,
                              void* d_out, int out_size, void* d_ws, size_t ws_size,
                              hipStream_t stream) {
  (void)in_sizes; (void)n_in; (void)out_size; (void)d_ws; (void)ws_size;
  Params p;
  p.cls_feat[0] = (const float*)d_in[0];
  p.reg_feat[0] = (const float*)d_in[1];
  p.cls_feat[1] = (const float*)d_in[2];
  p.reg_feat[1] = (const float*)d_in[3];
  p.cls_feat[2] = (const float*)d_in[4];
  p.reg_feat[2] = (const float*)d_in[5];
  for (int l = 0; l < 3; ++l) {
    const int base = 6 + l * 6;
    p.obj_w[l] = (const float*)d_in[base + 0];
    p.obj_b[l] = (const float*)d_in[base + 1];
    p.cls_w[l] = (const float*)d_in[base + 2];
    p.cls_b[l] = (const float*)d_in[base + 3];
    p.reg_w[l] = (const float*)d_in[base + 4];
    p.reg_b[l] = (const float*)d_in[base + 5];
  }
  p.out = (float*)d_out;

  dim3 grid(16 * 105, 2);  // x: batch*tile (80+20+5 per batch), y: 0=cls, 1=reg/obj
  dim3 block(320);         // 5 waves, one 16-row o-tile each
  hipLaunchKernelGGL(head_kernel, grid, block, 0, stream, p);
}